// Round 11
// baseline (269.037 us; speedup 1.0000x reference)
//
#include <hip/hip_runtime.h>
#include <hip/hip_fp16.h>
#include <math.h>

#define LSEQ 2048
#define NB 4
#define NH 8
#define DMID 512
#define CHK 128
#define SCALE 0.125f
#define DN 0.35355339059327373f   // 64^{-0.25}
#define DN2 0.125f                // DN*DN
#define EPS_ATTN 1e-5f
#define EPS_LN 1e-5f

typedef _Float16 f16x8 __attribute__((ext_vector_type(8)));
typedef _Float16 f16x4 __attribute__((ext_vector_type(4)));
typedef float f32x4 __attribute__((ext_vector_type(4)));

__device__ __forceinline__ void cvt16(const float* __restrict__ p,
                                      _Float16* __restrict__ dst) {
  float4 a = *(const float4*)p, b = *(const float4*)(p + 4);
  float4 c = *(const float4*)(p + 8), d = *(const float4*)(p + 12);
  f16x8 t0 = {(_Float16)a.x, (_Float16)a.y, (_Float16)a.z, (_Float16)a.w,
              (_Float16)b.x, (_Float16)b.y, (_Float16)b.z, (_Float16)b.w};
  f16x8 t1 = {(_Float16)c.x, (_Float16)c.y, (_Float16)c.z, (_Float16)c.w,
              (_Float16)d.x, (_Float16)d.y, (_Float16)d.z, (_Float16)d.w};
  *(f16x8*)dst = t0;
  *(f16x8*)(dst + 8) = t1;
}

// Diagnostic: encode ws_size (MiB) into the output if workspace too small.
__global__ void k_diag(float* out, int n, float val) {
  int i = blockIdx.x * 256 + threadIdx.x;
  if (i < n) out[i] = val;
}

// Once-per-launch: projT[n][k] = DN * proj[k][n], fp16 (64x256 -> 256x64).
__global__ __launch_bounds__(256) void k_ptr(const float* __restrict__ proj,
                                             __half* __restrict__ projT) {
  int e = blockIdx.x * 256 + threadIdx.x;   // 16384
  int n = e >> 6, k = e & 63;
  projT[e] = __float2half_rn(proj[k * 256 + n] * DN);
}

// ---------------------------------------------------------------------------
// S1 (MFMA): qkv = h @ w_qkv^T (NT, 8192x1536, K=512) -> q/k/v fp16 (bh,l,d).
// ---------------------------------------------------------------------------
__global__ __launch_bounds__(256) void k_qkv(
    const float* __restrict__ A, const float* __restrict__ Wq,
    __half* __restrict__ q, __half* __restrict__ k, __half* __restrict__ v) {
  __shared__ __align__(16) char smem[34816];
  _Float16* Ah = (_Float16*)smem;            // [128][40]
  _Float16* Bh = (_Float16*)(smem + 10240);  // [128][40]
  _Float16* Oh = (_Float16*)smem;            // [128][136] (epilogue alias)

  const int tid = threadIdx.x;
  const int row0 = blockIdx.x * 128;
  const int col0 = blockIdx.y * 128;
  const int lane = tid & 63, wv = tid >> 6;
  const int ln15 = lane & 15, quad = lane >> 4;
  const int m0 = wv * 32;
  const int srow = tid >> 1, sc = (tid & 1) * 16;

  f32x4 Cacc[2][8];
  const f32x4 z4 = {0.f, 0.f, 0.f, 0.f};
#pragma unroll
  for (int mi = 0; mi < 2; ++mi)
#pragma unroll
    for (int nt = 0; nt < 8; ++nt) Cacc[mi][nt] = z4;

  for (int kt = 0; kt < DMID; kt += 32) {
    cvt16(A + (size_t)(row0 + srow) * DMID + kt + sc, &Ah[srow * 40 + sc]);
    cvt16(Wq + (size_t)(col0 + srow) * DMID + kt + sc, &Bh[srow * 40 + sc]);
    __syncthreads();
    f16x8 a0 = *(const f16x8*)&Ah[(m0 + ln15) * 40 + quad * 8];
    f16x8 a1 = *(const f16x8*)&Ah[(m0 + 16 + ln15) * 40 + quad * 8];
#pragma unroll
    for (int nt = 0; nt < 8; ++nt) {
      f16x8 bf = *(const f16x8*)&Bh[(nt * 16 + ln15) * 40 + quad * 8];
      Cacc[0][nt] = __builtin_amdgcn_mfma_f32_16x16x32_f16(a0, bf, Cacc[0][nt], 0, 0, 0);
      Cacc[1][nt] = __builtin_amdgcn_mfma_f32_16x16x32_f16(a1, bf, Cacc[1][nt], 0, 0, 0);
    }
    __syncthreads();
  }
#pragma unroll
  for (int mi = 0; mi < 2; ++mi)
#pragma unroll
    for (int nt = 0; nt < 8; ++nt)
#pragma unroll
      for (int r = 0; r < 4; ++r)
        Oh[(m0 + mi * 16 + quad * 4 + r) * 136 + nt * 16 + ln15] =
            (_Float16)Cacc[mi][nt][r];
  __syncthreads();
  const int tr = tid >> 4, tc = tid & 15;
  const int col = col0 + tc * 8;
  const int hh = col / 192;
  const int rem = col - hh * 192;
  const int t = rem >> 6;
  const int d0 = rem & 63;
  __half* dstb = (t == 0) ? q : ((t == 1) ? k : v);
#pragma unroll
  for (int i = 0; i < 8; ++i) {
    int lrow = tr * 8 + i;
    int grow = row0 + lrow;
    int l = grow >> 2, bb = grow & 3;
    f16x8 val = *(const f16x8*)&Oh[lrow * 136 + tc * 8];
    *(f16x8*)((_Float16*)dstb + (((size_t)(bb * NH + hh) * LSEQ + l) << 6) + d0) = val;
  }
}

// ---------------------------------------------------------------------------
// S2 (MFMA): d = x @ (DN*proj) (65536x256, K=64) -> fp16; {diag, 1/rowsum}.
// 64-row blocks for occupancy (4 blocks/CU), Cacc[16] only.
// ---------------------------------------------------------------------------
__global__ __launch_bounds__(256, 4) void k_dgemm(
    const __half* __restrict__ qsrc, const __half* __restrict__ ksrc,
    const __half* __restrict__ projT, __half* __restrict__ dqd,
    __half* __restrict__ dkd, float2* __restrict__ nq,
    float2* __restrict__ nk) {
  __shared__ __align__(16) char smem[37376];
  _Float16* Bt = (_Float16*)smem;             // [256][72]
  float* g_l  = (float*)(smem + 36864);       // [64]
  float* ps_l = (float*)(smem + 37120);       // [64]
  _Float16* Oh = (_Float16*)smem;             // [64][136] epilogue alias

  const int tid = threadIdx.x;
  const __half* src = blockIdx.y ? ksrc : qsrc;
  __half* dst = blockIdx.y ? dkd : dqd;
  float2* nrm = blockIdx.y ? nk : nq;
  const size_t r0 = (size_t)blockIdx.x * 64;

  const int lane = tid & 63, wv = tid >> 6;
  const int ln15 = lane & 15, quad = lane >> 4;
  const int m0 = wv * 16;

#pragma unroll
  for (int it = 0; it < 8; ++it) {
    int e = it * 256 + tid;
    int n = e >> 3, seg = e & 7;
    *(f16x8*)&Bt[n * 72 + seg * 8] =
        *(const f16x8*)((const _Float16*)projT + n * 64 + seg * 8);
  }

  f16x8 afrag[2];
  float ss = 0.f;
  {
    const _Float16* rp = (const _Float16*)src + (r0 + m0 + ln15) * 64;
#pragma unroll
    for (int ks = 0; ks < 2; ++ks) {
      f16x8 x8 = *(const f16x8*)(rp + ks * 32 + quad * 8);
      afrag[ks] = x8;
#pragma unroll
      for (int j = 0; j < 8; ++j) {
        float xv = (float)x8[j];
        ss = fmaf(xv, xv, ss);
      }
    }
    ss += __shfl_xor(ss, 16);
    ss += __shfl_xor(ss, 32);
  }
  if (quad == 0) g_l[m0 + ln15] = 0.5f * DN2 * ss;
  __syncthreads();

  f32x4 Cacc[16];
  const f32x4 z4 = {0.f, 0.f, 0.f, 0.f};
#pragma unroll
  for (int nt = 0; nt < 16; ++nt) Cacc[nt] = z4;

#pragma unroll
  for (int ks = 0; ks < 2; ++ks) {
    f16x8 a0 = afrag[ks];
#pragma unroll
    for (int nt = 0; nt < 16; ++nt) {
      f16x8 bf = *(const f16x8*)&Bt[(nt * 16 + ln15) * 72 + ks * 32 + quad * 8];
      Cacc[nt] = __builtin_amdgcn_mfma_f32_16x16x32_f16(a0, bf, Cacc[nt], 0, 0, 0);
    }
  }

  float gv[4], pp[4];
#pragma unroll
  for (int r = 0; r < 4; ++r) {
    gv[r] = g_l[m0 + quad * 4 + r];
    pp[r] = 0.f;
  }
#pragma unroll
  for (int nt = 0; nt < 16; ++nt)
#pragma unroll
    for (int r = 0; r < 4; ++r) {
      float d = Cacc[nt][r];
      pp[r] += __expf(d - gv[r]) + __expf(-d - gv[r]);
    }
#pragma unroll
  for (int r = 0; r < 4; ++r) {
    float p = pp[r];
    p += __shfl_xor(p, 1); p += __shfl_xor(p, 2);
    p += __shfl_xor(p, 4); p += __shfl_xor(p, 8);
    if (ln15 == 0) ps_l[m0 + quad * 4 + r] = p;
  }

#pragma unroll
  for (int hf = 0; hf < 2; ++hf) {
    __syncthreads();
#pragma unroll
    for (int nt2 = 0; nt2 < 8; ++nt2) {
      int nt = hf * 8 + nt2;
#pragma unroll
      for (int r = 0; r < 4; ++r)
        Oh[(m0 + quad * 4 + r) * 136 + nt2 * 16 + ln15] =
            (_Float16)Cacc[nt][r];
    }
    __syncthreads();
#pragma unroll
    for (int it = 0; it < 4; ++it) {
      int e = it * 256 + tid;
      int row = e >> 4, seg = e & 15;
      *(f16x8*)((_Float16*)dst + (r0 + row) * 256 + hf * 128 + seg * 8) =
          *(const f16x8*)&Oh[row * 136 + seg * 8];
    }
  }
  if (tid < 64) nrm[r0 + tid] = make_float2(g_l[tid], 1.0f / ps_l[tid]);
}

// ---------------------------------------------------------------------------
// S3 (MFMA): per-chunk state, stored TRANSPOSED: KVt[cidx][d][feat].
// ---------------------------------------------------------------------------
__global__ __launch_bounds__(256) void k_kv(
    const __half* __restrict__ dk, const float2* __restrict__ nk,
    const __half* __restrict__ v, __half* __restrict__ KVt,
    float* __restrict__ Ks) {
  __shared__ __align__(16) char smem[53248];
  _Float16* kpT = (_Float16*)smem;            // [128][136] feat-major, s contig
  _Float16* Vt  = (_Float16*)(smem + 34816);  // [64][136]  d-major, s contig
  float* gk = (float*)(smem + 52224);         // [128]
  float* ik = (float*)(smem + 52736);         // [128]
  _Float16* Oh2 = (_Float16*)smem;            // [64][136] epilogue alias

  const int tid = threadIdx.x;
  const int cidx = blockIdx.x;
  const int i0 = blockIdx.y * 128;
  const float fsign = (i0 < 256) ? 1.f : -1.f;
  const int m0col = (i0 < 256) ? i0 : i0 - 256;
  const size_t rowbase = (size_t)cidx * CHK;

  if (tid < 128) {
    float2 n = nk[rowbase + tid];
    gk[tid] = n.x; ik[tid] = n.y;
  }
  __syncthreads();

  {
    const int srow = tid >> 1;
    const int scol = (tid & 1) * 64;
    float g = gk[srow], ivs = ik[srow];
    const _Float16* src =
        (const _Float16*)dk + (rowbase + srow) * 256 + m0col + scol;
#pragma unroll
    for (int it = 0; it < 8; ++it) {
      f16x8 d8 = *(const f16x8*)(src + it * 8);
#pragma unroll
      for (int j = 0; j < 8; ++j)
        kpT[(scol + it * 8 + j) * 136 + srow] =
            (_Float16)(__expf(fsign * (float)d8[j] - g) * ivs);
    }
  }
  {
    int s = tid & 127, dq0 = (tid >> 7) * 32;
    const _Float16* vsrc = (const _Float16*)v + (rowbase + s) * 64 + dq0;
#pragma unroll
    for (int b8 = 0; b8 < 4; ++b8) {
      f16x8 v8 = ((const f16x8*)vsrc)[b8];
#pragma unroll
      for (int j = 0; j < 8; ++j)
        Vt[(dq0 + b8 * 8 + j) * 136 + s] = v8[j];
    }
  }
  __syncthreads();

  const int lane = tid & 63, wv = tid >> 6;
  const int ln15 = lane & 15, quad = lane >> 4;
  const int m0 = wv * 32;

  f32x4 Cacc[2][4], Kacc[2];
  const f32x4 z4 = {0.f, 0.f, 0.f, 0.f};
#pragma unroll
  for (int mi = 0; mi < 2; ++mi) {
#pragma unroll
    for (int nt = 0; nt < 4; ++nt) Cacc[mi][nt] = z4;
    Kacc[mi] = z4;
  }
  f16x8 bone;
#pragma unroll
  for (int j = 0; j < 8; ++j)
    bone[j] = (ln15 == 0) ? (_Float16)1.0f : (_Float16)0.0f;

#pragma unroll
  for (int ks = 0; ks < 4; ++ks) {
    f16x8 a0 = *(const f16x8*)&kpT[(m0 + ln15) * 136 + ks * 32 + quad * 8];
    f16x8 a1 = *(const f16x8*)&kpT[(m0 + 16 + ln15) * 136 + ks * 32 + quad * 8];
#pragma unroll
    for (int nt = 0; nt < 4; ++nt) {
      f16x8 bV = *(const f16x8*)&Vt[(nt * 16 + ln15) * 136 + ks * 32 + quad * 8];
      Cacc[0][nt] = __builtin_amdgcn_mfma_f32_16x16x32_f16(a0, bV, Cacc[0][nt], 0, 0, 0);
      Cacc[1][nt] = __builtin_amdgcn_mfma_f32_16x16x32_f16(a1, bV, Cacc[1][nt], 0, 0, 0);
    }
    Kacc[0] = __builtin_amdgcn_mfma_f32_16x16x32_f16(a0, bone, Kacc[0], 0, 0, 0);
    Kacc[1] = __builtin_amdgcn_mfma_f32_16x16x32_f16(a1, bone, Kacc[1], 0, 0, 0);
  }

  if (ln15 == 0) {
#pragma unroll
    for (int mi = 0; mi < 2; ++mi)
#pragma unroll
      for (int r = 0; r < 4; ++r)
        Ks[(size_t)cidx * 512 + i0 + m0 + mi * 16 + quad * 4 + r] = Kacc[mi][r];
  }
  __syncthreads();
#pragma unroll
  for (int mi = 0; mi < 2; ++mi)
#pragma unroll
    for (int nt = 0; nt < 4; ++nt) {
      f16x4 pack = {(_Float16)Cacc[mi][nt][0], (_Float16)Cacc[mi][nt][1],
                    (_Float16)Cacc[mi][nt][2], (_Float16)Cacc[mi][nt][3]};
      *(f16x4*)&Oh2[(nt * 16 + ln15) * 136 + m0 + mi * 16 + quad * 4] = pack;
    }
  __syncthreads();
  {
    int d = tid >> 2, part = tid & 3;
    _Float16* dstp =
        (_Float16*)KVt + (size_t)cidx * 32768 + d * 512 + i0 + part * 32;
    const _Float16* srcp = &Oh2[d * 136 + part * 32];
#pragma unroll
    for (int j = 0; j < 4; ++j)
      *(f16x8*)(dstp + j * 8) = *(const f16x8*)(srcp + j * 8);
  }
}

// S3c: exclusive prefix over the 16 chunks (per bh) for KVt and Ks.
__global__ __launch_bounds__(256) void k_scan(__half2* __restrict__ KV2,
                                              float* __restrict__ Ks) {
  const int bh = blockIdx.x;
  const int e0 = blockIdx.y * 2048;
  for (int ee = 0; ee < 8; ++ee) {
    int e = e0 + ee * 256 + threadIdx.x;
    float ax = 0.f, ay = 0.f;
    __half2* p = KV2 + (size_t)bh * 16 * 16384 + e;
#pragma unroll
    for (int c = 0; c < 16; ++c) {
      float2 f = __half22float2(p[(size_t)c * 16384]);
      p[(size_t)c * 16384] = __floats2half2_rn(ax, ay);
      ax += f.x; ay += f.y;
    }
  }
  if (blockIdx.y == 0) {
    for (int ee = 0; ee < 2; ++ee) {
      int i = ee * 256 + threadIdx.x;
      float a = 0.f;
      float* p = Ks + (size_t)bh * 16 * 512 + i;
#pragma unroll
      for (int c = 0; c < 16; ++c) {
        float vv = p[c * 512];
        p[c * 512] = a;
        a += vv;
      }
    }
  }
}

// ---------------------------------------------------------------------------
// S4 (MFMA): grid (chunk, q-half). 4 waves x 16 q-rows = 64 rows/block.
// Causality asymmetry: th=0 needs only kp/V rows 0..63 and 4 S n-tiles.
// ---------------------------------------------------------------------------
__global__ __launch_bounds__(256, 4) void k_attn(
    const __half* __restrict__ dq, const __half* __restrict__ dk,
    const float2* __restrict__ nq, const float2* __restrict__ nk,
    const __half* __restrict__ v, const __half* __restrict__ KVt,
    const float* __restrict__ Kpre, float* __restrict__ outb) {
  __shared__ __align__(16) char smem[40320];
  float* gq_l   = (float*)(smem);             // [64]
  float* iq_l   = (float*)(smem + 256);
  float* gk_l   = (float*)(smem + 512);       // [128]
  float* ik_l   = (float*)(smem + 1024);
  float* den1_l = (float*)(smem + 1536);      // [64]
  float* den2_l = (float*)(smem + 1792);
  float* invd_l = (float*)(smem + 2048);
  float* KpT    = (float*)(smem + 2304);      // [32]
  _Float16* qpT = (_Float16*)(smem + 2432);   // [64][40]
  _Float16* kpT = (_Float16*)(smem + 7552);   // [128][40]
  _Float16* WT  = (_Float16*)(smem + 17792);  // [64][40]
  _Float16* S_h = (_Float16*)(smem + 2432);   // [64][136] (alias qpT/kpT/WT)
  _Float16* Vt  = (_Float16*)(smem + 22912);  // [64][136]

  const int tid = threadIdx.x;
  const int cidx = blockIdx.x;
  const int th = blockIdx.y;
  const int cc = cidx & 15, bh = cidx >> 4;
  const size_t rowb = (size_t)cidx * 128;
  const size_t rowt = rowb + th * 64;
  const int lane = tid & 63;
  const int wv = tid >> 6;
  const int ln15 = lane & 15;
  const int quad = lane >> 4;
  const int m0 = wv * 16;
  const int krows = th ? 128 : 64;  // causal: th=0 never touches kp rows >=64
  const int NS = th ? 8 : 4;

  if (tid < 64) {
    float2 n = nq[rowt + tid];
    gq_l[tid] = n.x; iq_l[tid] = n.y;
  }
  if (tid < krows) {
    float2 n2 = nk[rowb + tid];
    gk_l[tid] = n2.x; ik_l[tid] = n2.y;
  }
  __syncthreads();

  f32x4 Sacc[8], Oacc[4], Dacc;
  const f32x4 z4 = {0.f, 0.f, 0.f, 0.f};
#pragma unroll
  for (int nt = 0; nt < 8; ++nt) Sacc[nt] = z4;
#pragma unroll
  for (int nt = 0; nt < 4; ++nt) Oacc[nt] = z4;
  Dacc = z4;

  const int qrow = tid >> 2, qc = (tid & 3) * 8;     // qp staging
  const int krow = tid >> 1, kc = (tid & 1) * 16;    // kp staging

  for (int kt = 0; kt < 512; kt += 32) {
    const float sgn = (kt < 256) ? 1.f : -1.f;
    const int dbase = (kt < 256) ? kt : kt - 256;
    {
      const _Float16* src = (const _Float16*)dq + (rowt + qrow) * 256 + dbase + qc;
      float g = gq_l[qrow], iv = iq_l[qrow];
      f16x8 d0 = *(const f16x8*)(src);
      f16x8 t0;
#pragma unroll
      for (int j = 0; j < 8; ++j)
        t0[j] = (_Float16)(__expf(sgn * (float)d0[j] - g) * iv);
      *(f16x8*)&qpT[qrow * 40 + qc] = t0;
    }
    if (krow < krows) {
      const _Float16* src = (const _Float16*)dk + (rowb + krow) * 256 + dbase + kc;
      float g = gk_l[krow], iv = ik_l[krow];
      f16x8 d0 = *(const f16x8*)(src);
      f16x8 d1 = *(const f16x8*)(src + 8);
      f16x8 t0, t1;
#pragma unroll
      for (int j = 0; j < 8; ++j) {
        t0[j] = (_Float16)(__expf(sgn * (float)d0[j] - g) * iv);
        t1[j] = (_Float16)(__expf(sgn * (float)d1[j] - g) * iv);
      }
      *(f16x8*)&kpT[krow * 40 + kc] = t0;
      *(f16x8*)&kpT[krow * 40 + kc + 8] = t1;
    }
    {
      int d = tid >> 2, seg = tid & 3;
      *(f16x8*)&WT[d * 40 + seg * 8] =
          *(const f16x8*)((const _Float16*)KVt + (size_t)cidx * 32768 +
                          d * 512 + kt + seg * 8);
    }
    if (tid < 32) KpT[tid] = Kpre[(size_t)cidx * 512 + kt + tid];
    __syncthreads();

    f16x8 a0 = *(const f16x8*)&qpT[(m0 + ln15) * 40 + quad * 8];
    for (int nt = 0; nt < NS; ++nt) {
      f16x8 bf = *(const f16x8*)&kpT[(nt * 16 + ln15) * 40 + quad * 8];
      Sacc[nt] = __builtin_amdgcn_mfma_f32_16x16x32_f16(a0, bf, Sacc[nt], 0, 0, 0);
    }
#pragma unroll
    for (int nt = 0; nt < 4; ++nt) {
      f16x8 bw = *(const f16x8*)&WT[(nt * 16 + ln15) * 40 + quad * 8];
      Oacc[nt] = __builtin_amdgcn_mfma_f32_16x16x32_f16(a0, bw, Oacc[nt], 0, 0, 0);
    }
    {
      f16x8 bk;
#pragma unroll
      for (int j = 0; j < 8; ++j)
        bk[j] = (ln15 == 0) ? (_Float16)KpT[quad * 8 + j] : (_Float16)0.f;
      Dacc = __builtin_amdgcn_mfma_f32_16x16x32_f16(a0, bk, Dacc, 0, 0, 0);
    }
    __syncthreads();
  }

  if (ln15 == 0) {
#pragma unroll
    for (int r = 0; r < 4; ++r)
      den2_l[m0 + quad * 4 + r] = Dacc[r];
  }
  // mask + den1 + S_h (fp16 A-layout); only NS*16 columns are live
  {
    float dp[4] = {0.f, 0.f, 0.f, 0.f};
    for (int nt = 0; nt < NS; ++nt) {
      int s = nt * 16 + ln15;
#pragma unroll
      for (int r = 0; r < 4; ++r) {
        int tl = m0 + quad * 4 + r;
        float vsv = (s <= th * 64 + tl) ? Sacc[nt][r] : 0.f;
        dp[r] += vsv;
        S_h[tl * 136 + s] = (_Float16)vsv;
      }
    }
#pragma unroll
    for (int r = 0; r < 4; ++r) {
      float p = dp[r];
      p += __shfl_xor(p, 1); p += __shfl_xor(p, 2);
      p += __shfl_xor(p, 4); p += __shfl_xor(p, 8);
      if (ln15 == 0) den1_l[m0 + quad * 4 + r] = p;
    }
  }
  __syncthreads();
  if (tid < 64)
    invd_l[tid] = SCALE / (den1_l[tid] + den2_l[tid] + EPS_ATTN);
  {
    int s = tid & 127, d0v = (tid >> 7) * 32;
    if (s < krows) {
      const _Float16* vsrc = (const _Float16*)v + (rowb + s) * 64 + d0v;
      f16x8 v0 = ((const f16x8*)vsrc)[0];
      f16x8 v1 = ((const f16x8*)vsrc)[1];
      f16x8 v2 = ((const f16x8*)vsrc)[2];
      f16x8 v3 = ((const f16x8*)vsrc)[3];
#pragma unroll
      for (int j = 0; j < 8; ++j) {
        Vt[(d0v + j) * 136 + s] = v0[j];
        Vt[(d0v + 8 + j) * 136 + s] = v1[j];
        Vt[(d0v + 16 + j) * 136 + s] = v2[j];
        Vt[(d0v + 24 + j) * 136 + s] = v3[j];
      }
    }
  }
  __syncthreads();
  // O += S @ V  (th=0 only needs s<64)
  const int nks = th ? 4 : 2;
#pragma unroll 4
  for (int ks = 0; ks < nks; ++ks) {
    f16x8 aS0 = *(const f16x8*)&S_h[(m0 + ln15) * 136 + ks * 32 + quad * 8];
#pragma unroll
    for (int nt = 0; nt < 4; ++nt) {
      f16x8 bV = *(const f16x8*)&Vt[(nt * 16 + ln15) * 136 + ks * 32 + quad * 8];
      Oacc[nt] = __builtin_amdgcn_mfma_f32_16x16x32_f16(aS0, bV, Oacc[nt], 0, 0, 0);
    }
  }
  const int b = bh >> 3, hh = bh & 7;
  float ivv[4];
#pragma unroll
  for (int r = 0; r < 4; ++r)
    ivv[r] = invd_l[m0 + quad * 4 + r];
#pragma unroll
  for (int nt = 0; nt < 4; ++nt) {
    int dcol = nt * 16 + ln15;
#pragma unroll
    for (int r = 0; r < 4; ++r) {
      int tl = m0 + quad * 4 + r;
      int l = cc * 128 + th * 64 + tl;
      outb[((size_t)l * 4 + b) * 512 + hh * 64 + dcol] = Oacc[nt][r] * ivv[r];
    }
  }
}

// ---------------------------------------------------------------------------
// S5a (MFMA): x = out @ w_o^T + h (NT, 8192x512, K=512) -> d_out (fp32)
// ---------------------------------------------------------------------------
__global__ __launch_bounds__(256) void k_oproj(
    const float* __restrict__ A, const float* __restrict__ Wo,
    const float* __restrict__ hres, float* __restrict__ xout) {
  __shared__ __align__(16) char smem[34816];
  _Float16* Ah = (_Float16*)smem;            // [128][40]
  _Float16* Bh = (_Float16*)(smem + 10240);  // [128][40]
  _Float16* Oh = (_Float16*)smem;            // [128][136] (epilogue alias)

  const int tid = threadIdx.x;
  const int row0 = blockIdx.x * 128;
  const int col0 = blockIdx.y * 128;
  const int lane = tid & 63, wv = tid >> 6;
  const int ln15 = lane & 15, quad = lane >> 4;
  const int m0 = wv * 32;
  const int srow = tid >> 1, sc = (tid & 1) * 16;

  f32x4 Cacc[2][8];
  const f32x4 z4 = {0.f, 0.f, 0.f, 0.f};
#pragma unroll
  for (int mi = 0; mi < 2; ++mi)
#pragma unroll
    for (int nt = 0; nt < 8; ++nt) Cacc[mi][nt] = z4;

  for (int kt = 0; kt < DMID; kt += 32) {
    cvt16(A + (size_t)(row0 + srow) * DMID + kt + sc, &Ah[srow * 40 + sc]);
    cvt16(Wo + (size_t)(col0 + srow) * DMID + kt + sc, &Bh[srow * 40 + sc]);
    __syncthreads();
    f16x8 a0 = *(const f16x8*)&Ah[(m0 + ln15) * 40 + quad * 8];
    f16x8 a1 = *(const f16x8*)&Ah[(m0 + 16 + ln15) * 40 + quad * 8];
#pragma unroll
    for (int nt = 0; nt < 8; ++nt) {
      f16x8 bf = *(const f16x8*)&Bh[(nt * 16 + ln15) * 40 + quad * 8];
      Cacc[0][nt] = __builtin_amdgcn_mfma_f32_16x16x32_f16(a0, bf, Cacc[0][nt], 0, 0, 0);
      Cacc[1][nt] = __builtin_amdgcn_mfma_f32_16x16x32_f16(a1, bf, Cacc[1][nt], 0, 0, 0);
    }
    __syncthreads();
  }
#pragma unroll
  for (int mi = 0; mi < 2; ++mi)
#pragma unroll
    for (int nt = 0; nt < 8; ++nt)
#pragma unroll
      for (int r = 0; r < 4; ++r)
        Oh[(m0 + mi * 16 + quad * 4 + r) * 136 + nt * 16 + ln15] =
            (_Float16)Cacc[mi][nt][r];
  __syncthreads();
  const int tr = tid >> 4, tc = tid & 15;
#pragma unroll
  for (int i = 0; i < 8; ++i) {
    int lrow = tr * 8 + i;
    int grow = row0 + lrow;
    size_t base = (size_t)grow * 512 + col0 + tc * 8;
    f16x8 o = *(const f16x8*)&Oh[lrow * 136 + tc * 8];
    float4 h0 = *(const float4*)(hres + base);
    float4 h1 = *(const float4*)(hres + base + 4);
    *(float4*)(xout + base) =
        make_float4((float)o[0] + h0.x, (float)o[1] + h0.y,
                    (float)o[2] + h0.z, (float)o[3] + h0.w);
    *(float4*)(xout + base + 4) =
        make_float4((float)o[4] + h1.x, (float)o[5] + h1.y,
                    (float)o[6] + h1.z, (float)o[7] + h1.w);
  }
}

// S5b: in-place LayerNorm over last dim (512).
__global__ __launch_bounds__(256) void k_ln(float* __restrict__ x,
                                            const float* __restrict__ g,
                                            const float* __restrict__ bta) {
  __shared__ float ws_[4], wq_[4];
  const int row = blockIdx.x;
  const int tid = threadIdx.x;
  float2 vv = *(const float2*)(x + (size_t)row * 512 + tid * 2);
  float s = vv.x + vv.y;
  float sq = vv.x * vv.x + vv.y * vv.y;
#pragma unroll
  for (int off = 1; off < 64; off <<= 1) {
    s += __shfl_xor(s, off, 64);
    sq += __shfl_xor(sq, off, 64);
  }
  if ((tid & 63) == 0) { ws_[tid >> 6] = s; wq_[tid >> 6] = sq; }
  __syncthreads();
  s = ws_[0] + ws_[1] + ws_[2] + ws_[3];
  sq = wq_[0] + wq_[1] + wq_[2] + wq_[3];
  float mu = s * (1.f / 512.f);
  float var = sq * (1.f / 512.f) - mu * mu;
  float rstd = rsqrtf(var + EPS_LN);
  int c = tid * 2;
  float2 o;
  o.x = (vv.x - mu) * rstd * g[c] + bta[c];
  o.y = (vv.y - mu) * rstd * g[c + 1] + bta[c + 1];
  *(float2*)(x + (size_t)row * 512 + c) = o;
}

// ---------------------------------------------------------------------------
extern "C" void kernel_launch(void* const* d_in, const int* in_sizes, int n_in,
                              void* d_out, int out_size, void* d_ws,
                              size_t ws_size, hipStream_t stream) {
  const float* h    = (const float*)d_in[0];
  const float* wqkv = (const float*)d_in[1];
  const float* wo   = (const float*)d_in[2];
  const float* g    = (const float*)d_in[3];
  const float* bta  = (const float*)d_in[4];
  const float* proj = (const float*)d_in[5];
  float* out = (float*)d_out;
  char* wsb = (char*)d_ws;

  __half* q   = (__half*)(wsb + 0);           //  8,388,608 B
  __half* kb  = (__half*)(wsb + 8388608);     //  8,388,608 B
  __half* vb  = (__half*)(wsb + 16777216);    //  8,388,608 B
  __half* dq  = (__half*)(wsb + 25165824);    // 33,554,432 B
  __half* dk  = (__half*)(wsb + 58720256);    // 33,554,432 B
  float2* nq  = (float2*)(wsb + 92274688);    //    524,288 B
  float2* nk  = (float2*)(wsb + 92798976);    //    524,288 B
  __half* KVt = (__half*)(wsb + 93323264);    // 33,554,432 B  (cidx,d,feat)
  float*  Ks  = (float*)(wsb + 126877696);    //  1,048,576 B
  __half* pT  = (__half*)(wsb + 127926272);   //     32,768 B
  float* outb = (float*)(wsb + 0);            // aliases q+kb (dead by then)

  if (ws_size < 127959040ull) {
    float val = 1000.0f + (float)(ws_size >> 20);
    k_diag<<<(out_size + 255) / 256, 256, 0, stream>>>(out, out_size, val);
    return;
  }

  k_ptr  <<<dim3(64), 256, 0, stream>>>(proj, pT);
  k_qkv  <<<dim3(64, 12), 256, 0, stream>>>(h, wqkv, q, kb, vb);
  k_dgemm<<<dim3(1024, 2), 256, 0, stream>>>(q, kb, pT, dq, dk, nq, nk);
  k_kv   <<<dim3(512, 4), 256, 0, stream>>>(dk, nk, vb, KVt, Ks);
  k_scan <<<dim3(32, 8), 256, 0, stream>>>((__half2*)KVt, Ks);
  k_attn <<<dim3(512, 2), 256, 0, stream>>>(dq, dk, nq, nk, vb, KVt, Ks, outb);
  k_oproj<<<dim3(64, 4), 256, 0, stream>>>(outb, wo, h, out);
  k_ln   <<<dim3(8192), 256, 0, stream>>>(out, g, bta);
}

// Round 12
// 257.378 us; speedup vs baseline: 1.0453x; 1.0453x over previous
//
#include <hip/hip_runtime.h>
#include <hip/hip_fp16.h>
#include <math.h>

#define LSEQ 2048
#define NB 4
#define NH 8
#define DMID 512
#define CHK 128
#define SCALE 0.125f
#define DN 0.35355339059327373f   // 64^{-0.25}
#define DN2 0.125f                // DN*DN
#define EPS_ATTN 1e-5f
#define EPS_LN 1e-5f

typedef _Float16 f16x8 __attribute__((ext_vector_type(8)));
typedef _Float16 f16x4 __attribute__((ext_vector_type(4)));
typedef float f32x4 __attribute__((ext_vector_type(4)));

__device__ __forceinline__ void cvt16(const float* __restrict__ p,
                                      _Float16* __restrict__ dst) {
  float4 a = *(const float4*)p, b = *(const float4*)(p + 4);
  float4 c = *(const float4*)(p + 8), d = *(const float4*)(p + 12);
  f16x8 t0 = {(_Float16)a.x, (_Float16)a.y, (_Float16)a.z, (_Float16)a.w,
              (_Float16)b.x, (_Float16)b.y, (_Float16)b.z, (_Float16)b.w};
  f16x8 t1 = {(_Float16)c.x, (_Float16)c.y, (_Float16)c.z, (_Float16)c.w,
              (_Float16)d.x, (_Float16)d.y, (_Float16)d.z, (_Float16)d.w};
  *(f16x8*)dst = t0;
  *(f16x8*)(dst + 8) = t1;
}

// Diagnostic: encode ws_size (MiB) into the output if workspace too small.
__global__ void k_diag(float* out, int n, float val) {
  int i = blockIdx.x * 256 + threadIdx.x;
  if (i < n) out[i] = val;
}

// Once-per-launch: projT[n][k] = DN * proj[k][n], fp16 (64x256 -> 256x64).
__global__ __launch_bounds__(256) void k_ptr(const float* __restrict__ proj,
                                             __half* __restrict__ projT) {
  int e = blockIdx.x * 256 + threadIdx.x;   // 16384
  int n = e >> 6, k = e & 63;
  projT[e] = __float2half_rn(proj[k * 256 + n] * DN);
}

// ---------------------------------------------------------------------------
// S1 (MFMA): qkv = h @ w_qkv^T (NT, 8192x1536, K=512) -> q/k/v fp16 (bh,l,d).
// ---------------------------------------------------------------------------
__global__ __launch_bounds__(256) void k_qkv(
    const float* __restrict__ A, const float* __restrict__ Wq,
    __half* __restrict__ q, __half* __restrict__ k, __half* __restrict__ v) {
  __shared__ __align__(16) char smem[34816];
  _Float16* Ah = (_Float16*)smem;            // [128][40]
  _Float16* Bh = (_Float16*)(smem + 10240);  // [128][40]
  _Float16* Oh = (_Float16*)smem;            // [128][136] (epilogue alias)

  const int tid = threadIdx.x;
  const int row0 = blockIdx.x * 128;
  const int col0 = blockIdx.y * 128;
  const int lane = tid & 63, wv = tid >> 6;
  const int ln15 = lane & 15, quad = lane >> 4;
  const int m0 = wv * 32;
  const int srow = tid >> 1, sc = (tid & 1) * 16;

  f32x4 Cacc[2][8];
  const f32x4 z4 = {0.f, 0.f, 0.f, 0.f};
#pragma unroll
  for (int mi = 0; mi < 2; ++mi)
#pragma unroll
    for (int nt = 0; nt < 8; ++nt) Cacc[mi][nt] = z4;

  for (int kt = 0; kt < DMID; kt += 32) {
    cvt16(A + (size_t)(row0 + srow) * DMID + kt + sc, &Ah[srow * 40 + sc]);
    cvt16(Wq + (size_t)(col0 + srow) * DMID + kt + sc, &Bh[srow * 40 + sc]);
    __syncthreads();
    f16x8 a0 = *(const f16x8*)&Ah[(m0 + ln15) * 40 + quad * 8];
    f16x8 a1 = *(const f16x8*)&Ah[(m0 + 16 + ln15) * 40 + quad * 8];
#pragma unroll
    for (int nt = 0; nt < 8; ++nt) {
      f16x8 bf = *(const f16x8*)&Bh[(nt * 16 + ln15) * 40 + quad * 8];
      Cacc[0][nt] = __builtin_amdgcn_mfma_f32_16x16x32_f16(a0, bf, Cacc[0][nt], 0, 0, 0);
      Cacc[1][nt] = __builtin_amdgcn_mfma_f32_16x16x32_f16(a1, bf, Cacc[1][nt], 0, 0, 0);
    }
    __syncthreads();
  }
#pragma unroll
  for (int mi = 0; mi < 2; ++mi)
#pragma unroll
    for (int nt = 0; nt < 8; ++nt)
#pragma unroll
      for (int r = 0; r < 4; ++r)
        Oh[(m0 + mi * 16 + quad * 4 + r) * 136 + nt * 16 + ln15] =
            (_Float16)Cacc[mi][nt][r];
  __syncthreads();
  const int tr = tid >> 4, tc = tid & 15;
  const int col = col0 + tc * 8;
  const int hh = col / 192;
  const int rem = col - hh * 192;
  const int t = rem >> 6;
  const int d0 = rem & 63;
  __half* dstb = (t == 0) ? q : ((t == 1) ? k : v);
#pragma unroll
  for (int i = 0; i < 8; ++i) {
    int lrow = tr * 8 + i;
    int grow = row0 + lrow;
    int l = grow >> 2, bb = grow & 3;
    f16x8 val = *(const f16x8*)&Oh[lrow * 136 + tc * 8];
    *(f16x8*)((_Float16*)dstb + (((size_t)(bb * NH + hh) * LSEQ + l) << 6) + d0) = val;
  }
}

// ---------------------------------------------------------------------------
// S2 (MFMA): d = x @ (DN*proj) (65536x256, K=64) -> fp16; {diag, 1/rowsum}.
// ---------------------------------------------------------------------------
__global__ __launch_bounds__(256, 4) void k_dgemm(
    const __half* __restrict__ qsrc, const __half* __restrict__ ksrc,
    const __half* __restrict__ projT, __half* __restrict__ dqd,
    __half* __restrict__ dkd, float2* __restrict__ nq,
    float2* __restrict__ nk) {
  __shared__ __align__(16) char smem[37376];
  _Float16* Bt = (_Float16*)smem;             // [256][72]
  float* g_l  = (float*)(smem + 36864);       // [64]
  float* ps_l = (float*)(smem + 37120);       // [64]
  _Float16* Oh = (_Float16*)smem;             // [64][136] epilogue alias

  const int tid = threadIdx.x;
  const __half* src = blockIdx.y ? ksrc : qsrc;
  __half* dst = blockIdx.y ? dkd : dqd;
  float2* nrm = blockIdx.y ? nk : nq;
  const size_t r0 = (size_t)blockIdx.x * 64;

  const int lane = tid & 63, wv = tid >> 6;
  const int ln15 = lane & 15, quad = lane >> 4;
  const int m0 = wv * 16;

#pragma unroll
  for (int it = 0; it < 8; ++it) {
    int e = it * 256 + tid;
    int n = e >> 3, seg = e & 7;
    *(f16x8*)&Bt[n * 72 + seg * 8] =
        *(const f16x8*)((const _Float16*)projT + n * 64 + seg * 8);
  }

  f16x8 afrag[2];
  float ss = 0.f;
  {
    const _Float16* rp = (const _Float16*)src + (r0 + m0 + ln15) * 64;
#pragma unroll
    for (int ks = 0; ks < 2; ++ks) {
      f16x8 x8 = *(const f16x8*)(rp + ks * 32 + quad * 8);
      afrag[ks] = x8;
#pragma unroll
      for (int j = 0; j < 8; ++j) {
        float xv = (float)x8[j];
        ss = fmaf(xv, xv, ss);
      }
    }
    ss += __shfl_xor(ss, 16);
    ss += __shfl_xor(ss, 32);
  }
  if (quad == 0) g_l[m0 + ln15] = 0.5f * DN2 * ss;
  __syncthreads();

  f32x4 Cacc[16];
  const f32x4 z4 = {0.f, 0.f, 0.f, 0.f};
#pragma unroll
  for (int nt = 0; nt < 16; ++nt) Cacc[nt] = z4;

#pragma unroll
  for (int ks = 0; ks < 2; ++ks) {
    f16x8 a0 = afrag[ks];
#pragma unroll
    for (int nt = 0; nt < 16; ++nt) {
      f16x8 bf = *(const f16x8*)&Bt[(nt * 16 + ln15) * 72 + ks * 32 + quad * 8];
      Cacc[nt] = __builtin_amdgcn_mfma_f32_16x16x32_f16(a0, bf, Cacc[nt], 0, 0, 0);
    }
  }

  float gv[4], pp[4];
#pragma unroll
  for (int r = 0; r < 4; ++r) {
    gv[r] = g_l[m0 + quad * 4 + r];
    pp[r] = 0.f;
  }
#pragma unroll
  for (int nt = 0; nt < 16; ++nt)
#pragma unroll
    for (int r = 0; r < 4; ++r) {
      float d = Cacc[nt][r];
      pp[r] += __expf(d - gv[r]) + __expf(-d - gv[r]);
    }
#pragma unroll
  for (int r = 0; r < 4; ++r) {
    float p = pp[r];
    p += __shfl_xor(p, 1); p += __shfl_xor(p, 2);
    p += __shfl_xor(p, 4); p += __shfl_xor(p, 8);
    if (ln15 == 0) ps_l[m0 + quad * 4 + r] = p;
  }

#pragma unroll
  for (int hf = 0; hf < 2; ++hf) {
    __syncthreads();
#pragma unroll
    for (int nt2 = 0; nt2 < 8; ++nt2) {
      int nt = hf * 8 + nt2;
#pragma unroll
      for (int r = 0; r < 4; ++r)
        Oh[(m0 + quad * 4 + r) * 136 + nt2 * 16 + ln15] =
            (_Float16)Cacc[nt][r];
    }
    __syncthreads();
#pragma unroll
    for (int it = 0; it < 4; ++it) {
      int e = it * 256 + tid;
      int row = e >> 4, seg = e & 15;
      *(f16x8*)((_Float16*)dst + (r0 + row) * 256 + hf * 128 + seg * 8) =
          *(const f16x8*)&Oh[row * 136 + seg * 8];
    }
  }
  if (tid < 64) nrm[r0 + tid] = make_float2(g_l[tid], 1.0f / ps_l[tid]);
}

// ---------------------------------------------------------------------------
// S3 (MFMA): per-chunk state, stored TRANSPOSED: KVt[cidx][d][feat].
// ---------------------------------------------------------------------------
__global__ __launch_bounds__(256) void k_kv(
    const __half* __restrict__ dk, const float2* __restrict__ nk,
    const __half* __restrict__ v, __half* __restrict__ KVt,
    float* __restrict__ Ks) {
  __shared__ __align__(16) char smem[53248];
  _Float16* kpT = (_Float16*)smem;            // [128][136] feat-major, s contig
  _Float16* Vt  = (_Float16*)(smem + 34816);  // [64][136]  d-major, s contig
  float* gk = (float*)(smem + 52224);         // [128]
  float* ik = (float*)(smem + 52736);         // [128]
  _Float16* Oh2 = (_Float16*)smem;            // [64][136] epilogue alias

  const int tid = threadIdx.x;
  const int cidx = blockIdx.x;
  const int i0 = blockIdx.y * 128;
  const float fsign = (i0 < 256) ? 1.f : -1.f;
  const int m0col = (i0 < 256) ? i0 : i0 - 256;
  const size_t rowbase = (size_t)cidx * CHK;

  if (tid < 128) {
    float2 n = nk[rowbase + tid];
    gk[tid] = n.x; ik[tid] = n.y;
  }
  __syncthreads();

  {
    const int srow = tid >> 1;
    const int scol = (tid & 1) * 64;
    float g = gk[srow], ivs = ik[srow];
    const _Float16* src =
        (const _Float16*)dk + (rowbase + srow) * 256 + m0col + scol;
#pragma unroll
    for (int it = 0; it < 8; ++it) {
      f16x8 d8 = *(const f16x8*)(src + it * 8);
#pragma unroll
      for (int j = 0; j < 8; ++j)
        kpT[(scol + it * 8 + j) * 136 + srow] =
            (_Float16)(__expf(fsign * (float)d8[j] - g) * ivs);
    }
  }
  {
    int s = tid & 127, dq0 = (tid >> 7) * 32;
    const _Float16* vsrc = (const _Float16*)v + (rowbase + s) * 64 + dq0;
#pragma unroll
    for (int b8 = 0; b8 < 4; ++b8) {
      f16x8 v8 = ((const f16x8*)vsrc)[b8];
#pragma unroll
      for (int j = 0; j < 8; ++j)
        Vt[(dq0 + b8 * 8 + j) * 136 + s] = v8[j];
    }
  }
  __syncthreads();

  const int lane = tid & 63, wv = tid >> 6;
  const int ln15 = lane & 15, quad = lane >> 4;
  const int m0 = wv * 32;

  f32x4 Cacc[2][4], Kacc[2];
  const f32x4 z4 = {0.f, 0.f, 0.f, 0.f};
#pragma unroll
  for (int mi = 0; mi < 2; ++mi) {
#pragma unroll
    for (int nt = 0; nt < 4; ++nt) Cacc[mi][nt] = z4;
    Kacc[mi] = z4;
  }
  f16x8 bone;
#pragma unroll
  for (int j = 0; j < 8; ++j)
    bone[j] = (ln15 == 0) ? (_Float16)1.0f : (_Float16)0.0f;

#pragma unroll
  for (int ks = 0; ks < 4; ++ks) {
    f16x8 a0 = *(const f16x8*)&kpT[(m0 + ln15) * 136 + ks * 32 + quad * 8];
    f16x8 a1 = *(const f16x8*)&kpT[(m0 + 16 + ln15) * 136 + ks * 32 + quad * 8];
#pragma unroll
    for (int nt = 0; nt < 4; ++nt) {
      f16x8 bV = *(const f16x8*)&Vt[(nt * 16 + ln15) * 136 + ks * 32 + quad * 8];
      Cacc[0][nt] = __builtin_amdgcn_mfma_f32_16x16x32_f16(a0, bV, Cacc[0][nt], 0, 0, 0);
      Cacc[1][nt] = __builtin_amdgcn_mfma_f32_16x16x32_f16(a1, bV, Cacc[1][nt], 0, 0, 0);
    }
    Kacc[0] = __builtin_amdgcn_mfma_f32_16x16x32_f16(a0, bone, Kacc[0], 0, 0, 0);
    Kacc[1] = __builtin_amdgcn_mfma_f32_16x16x32_f16(a1, bone, Kacc[1], 0, 0, 0);
  }

  if (ln15 == 0) {
#pragma unroll
    for (int mi = 0; mi < 2; ++mi)
#pragma unroll
      for (int r = 0; r < 4; ++r)
        Ks[(size_t)cidx * 512 + i0 + m0 + mi * 16 + quad * 4 + r] = Kacc[mi][r];
  }
  __syncthreads();
#pragma unroll
  for (int mi = 0; mi < 2; ++mi)
#pragma unroll
    for (int nt = 0; nt < 4; ++nt) {
      f16x4 pack = {(_Float16)Cacc[mi][nt][0], (_Float16)Cacc[mi][nt][1],
                    (_Float16)Cacc[mi][nt][2], (_Float16)Cacc[mi][nt][3]};
      *(f16x4*)&Oh2[(nt * 16 + ln15) * 136 + m0 + mi * 16 + quad * 4] = pack;
    }
  __syncthreads();
  {
    int d = tid >> 2, part = tid & 3;
    _Float16* dstp =
        (_Float16*)KVt + (size_t)cidx * 32768 + d * 512 + i0 + part * 32;
    const _Float16* srcp = &Oh2[d * 136 + part * 32];
#pragma unroll
    for (int j = 0; j < 4; ++j)
      *(f16x8*)(dstp + j * 8) = *(const f16x8*)(srcp + j * 8);
  }
}

// S3c: exclusive prefix over the 16 chunks (per bh) for KVt and Ks.
__global__ __launch_bounds__(256) void k_scan(__half2* __restrict__ KV2,
                                              float* __restrict__ Ks) {
  const int bh = blockIdx.x;
  const int e0 = blockIdx.y * 2048;
  for (int ee = 0; ee < 8; ++ee) {
    int e = e0 + ee * 256 + threadIdx.x;
    float ax = 0.f, ay = 0.f;
    __half2* p = KV2 + (size_t)bh * 16 * 16384 + e;
#pragma unroll
    for (int c = 0; c < 16; ++c) {
      float2 f = __half22float2(p[(size_t)c * 16384]);
      p[(size_t)c * 16384] = __floats2half2_rn(ax, ay);
      ax += f.x; ay += f.y;
    }
  }
  if (blockIdx.y == 0) {
    for (int ee = 0; ee < 2; ++ee) {
      int i = ee * 256 + threadIdx.x;
      float a = 0.f;
      float* p = Ks + (size_t)bh * 16 * 512 + i;
#pragma unroll
      for (int c = 0; c < 16; ++c) {
        float vv = p[c * 512];
        p[c * 512] = a;
        a += vv;
      }
    }
  }
}

// ---------------------------------------------------------------------------
// S4 (MFMA): grid (chunk, q-half). Template on TH so all loop bounds are
// compile-time (full unroll); th=0 uses only kp/V rows 0..63, 4 S n-tiles.
// ---------------------------------------------------------------------------
template <int TH>
__device__ __forceinline__ void attn_body(
    const __half* __restrict__ dq, const __half* __restrict__ dk,
    const float2* __restrict__ nq, const float2* __restrict__ nk,
    const __half* __restrict__ v, const __half* __restrict__ KVt,
    const float* __restrict__ Kpre, float* __restrict__ outb, char* smem) {
  constexpr int KROWS = TH ? 128 : 64;
  constexpr int NS = TH ? 8 : 4;
  constexpr int NKS = TH ? 4 : 2;

  float* gq_l   = (float*)(smem);             // [64]
  float* iq_l   = (float*)(smem + 256);
  float* gk_l   = (float*)(smem + 512);       // [128]
  float* ik_l   = (float*)(smem + 1024);
  float* den1_l = (float*)(smem + 1536);      // [64]
  float* den2_l = (float*)(smem + 1792);
  float* invd_l = (float*)(smem + 2048);
  float* KpT    = (float*)(smem + 2304);      // [32]
  _Float16* qpT = (_Float16*)(smem + 2432);   // [64][40]
  _Float16* kpT = (_Float16*)(smem + 7552);   // [128][40]
  _Float16* WT  = (_Float16*)(smem + 17792);  // [64][40]
  _Float16* S_h = (_Float16*)(smem + 2432);   // [64][136] (alias)
  _Float16* Vt  = (_Float16*)(smem + 22912);  // [64][136]

  const int tid = threadIdx.x;
  const int cidx = blockIdx.x;
  const int cc = cidx & 15, bh = cidx >> 4;
  const size_t rowb = (size_t)cidx * 128;
  const size_t rowt = rowb + TH * 64;
  const int lane = tid & 63;
  const int wv = tid >> 6;
  const int ln15 = lane & 15;
  const int quad = lane >> 4;
  const int m0 = wv * 16;

  if (tid < 64) {
    float2 n = nq[rowt + tid];
    gq_l[tid] = n.x; iq_l[tid] = n.y;
  }
  if (tid < KROWS) {
    float2 n2 = nk[rowb + tid];
    gk_l[tid] = n2.x; ik_l[tid] = n2.y;
  }
  __syncthreads();

  f32x4 Sacc[NS], Oacc[4], Dacc;
  const f32x4 z4 = {0.f, 0.f, 0.f, 0.f};
#pragma unroll
  for (int nt = 0; nt < NS; ++nt) Sacc[nt] = z4;
#pragma unroll
  for (int nt = 0; nt < 4; ++nt) Oacc[nt] = z4;
  Dacc = z4;

  const int qrow = tid >> 2, qc = (tid & 3) * 8;
  const int krow = tid >> 1, kc = (tid & 1) * 16;

  for (int kt = 0; kt < 512; kt += 32) {
    const float sgn = (kt < 256) ? 1.f : -1.f;
    const int dbase = (kt < 256) ? kt : kt - 256;
    {
      const _Float16* src = (const _Float16*)dq + (rowt + qrow) * 256 + dbase + qc;
      float g = gq_l[qrow], iv = iq_l[qrow];
      f16x8 d0 = *(const f16x8*)(src);
      f16x8 t0;
#pragma unroll
      for (int j = 0; j < 8; ++j)
        t0[j] = (_Float16)(__expf(sgn * (float)d0[j] - g) * iv);
      *(f16x8*)&qpT[qrow * 40 + qc] = t0;
    }
    if (TH == 1 || krow < 64) {
      const _Float16* src = (const _Float16*)dk + (rowb + krow) * 256 + dbase + kc;
      float g = gk_l[krow], iv = ik_l[krow];
      f16x8 d0 = *(const f16x8*)(src);
      f16x8 d1 = *(const f16x8*)(src + 8);
      f16x8 t0, t1;
#pragma unroll
      for (int j = 0; j < 8; ++j) {
        t0[j] = (_Float16)(__expf(sgn * (float)d0[j] - g) * iv);
        t1[j] = (_Float16)(__expf(sgn * (float)d1[j] - g) * iv);
      }
      *(f16x8*)&kpT[krow * 40 + kc] = t0;
      *(f16x8*)&kpT[krow * 40 + kc + 8] = t1;
    }
    {
      int d = tid >> 2, seg = tid & 3;
      *(f16x8*)&WT[d * 40 + seg * 8] =
          *(const f16x8*)((const _Float16*)KVt + (size_t)cidx * 32768 +
                          d * 512 + kt + seg * 8);
    }
    if (tid < 32) KpT[tid] = Kpre[(size_t)cidx * 512 + kt + tid];
    __syncthreads();

    f16x8 a0 = *(const f16x8*)&qpT[(m0 + ln15) * 40 + quad * 8];
#pragma unroll
    for (int nt = 0; nt < NS; ++nt) {
      f16x8 bf = *(const f16x8*)&kpT[(nt * 16 + ln15) * 40 + quad * 8];
      Sacc[nt] = __builtin_amdgcn_mfma_f32_16x16x32_f16(a0, bf, Sacc[nt], 0, 0, 0);
    }
#pragma unroll
    for (int nt = 0; nt < 4; ++nt) {
      f16x8 bw = *(const f16x8*)&WT[(nt * 16 + ln15) * 40 + quad * 8];
      Oacc[nt] = __builtin_amdgcn_mfma_f32_16x16x32_f16(a0, bw, Oacc[nt], 0, 0, 0);
    }
    {
      f16x8 bk;
#pragma unroll
      for (int j = 0; j < 8; ++j)
        bk[j] = (ln15 == 0) ? (_Float16)KpT[quad * 8 + j] : (_Float16)0.f;
      Dacc = __builtin_amdgcn_mfma_f32_16x16x32_f16(a0, bk, Dacc, 0, 0, 0);
    }
    __syncthreads();
  }

  if (ln15 == 0) {
#pragma unroll
    for (int r = 0; r < 4; ++r)
      den2_l[m0 + quad * 4 + r] = Dacc[r];
  }
  {
    float dp[4] = {0.f, 0.f, 0.f, 0.f};
#pragma unroll
    for (int nt = 0; nt < NS; ++nt) {
      int s = nt * 16 + ln15;
#pragma unroll
      for (int r = 0; r < 4; ++r) {
        int tl = m0 + quad * 4 + r;
        float vsv = (s <= TH * 64 + tl) ? Sacc[nt][r] : 0.f;
        dp[r] += vsv;
        S_h[tl * 136 + s] = (_Float16)vsv;
      }
    }
#pragma unroll
    for (int r = 0; r < 4; ++r) {
      float p = dp[r];
      p += __shfl_xor(p, 1); p += __shfl_xor(p, 2);
      p += __shfl_xor(p, 4); p += __shfl_xor(p, 8);
      if (ln15 == 0) den1_l[m0 + quad * 4 + r] = p;
    }
  }
  __syncthreads();
  if (tid < 64)
    invd_l[tid] = SCALE / (den1_l[tid] + den2_l[tid] + EPS_ATTN);
  {
    int s = tid & 127, d0v = (tid >> 7) * 32;
    if (TH == 1 || s < 64) {
      const _Float16* vsrc = (const _Float16*)v + (rowb + s) * 64 + d0v;
      f16x8 v0 = ((const f16x8*)vsrc)[0];
      f16x8 v1 = ((const f16x8*)vsrc)[1];
      f16x8 v2 = ((const f16x8*)vsrc)[2];
      f16x8 v3 = ((const f16x8*)vsrc)[3];
#pragma unroll
      for (int j = 0; j < 8; ++j) {
        Vt[(d0v + j) * 136 + s] = v0[j];
        Vt[(d0v + 8 + j) * 136 + s] = v1[j];
        Vt[(d0v + 16 + j) * 136 + s] = v2[j];
        Vt[(d0v + 24 + j) * 136 + s] = v3[j];
      }
    }
  }
  __syncthreads();
#pragma unroll
  for (int ks = 0; ks < NKS; ++ks) {
    f16x8 aS0 = *(const f16x8*)&S_h[(m0 + ln15) * 136 + ks * 32 + quad * 8];
#pragma unroll
    for (int nt = 0; nt < 4; ++nt) {
      f16x8 bV = *(const f16x8*)&Vt[(nt * 16 + ln15) * 136 + ks * 32 + quad * 8];
      Oacc[nt] = __builtin_amdgcn_mfma_f32_16x16x32_f16(aS0, bV, Oacc[nt], 0, 0, 0);
    }
  }
  const int b = bh >> 3, hh = bh & 7;
  float ivv[4];
#pragma unroll
  for (int r = 0; r < 4; ++r)
    ivv[r] = invd_l[m0 + quad * 4 + r];
#pragma unroll
  for (int nt = 0; nt < 4; ++nt) {
    int dcol = nt * 16 + ln15;
#pragma unroll
    for (int r = 0; r < 4; ++r) {
      int tl = m0 + quad * 4 + r;
      int l = cc * 128 + TH * 64 + tl;
      outb[((size_t)l * 4 + b) * 512 + hh * 64 + dcol] = Oacc[nt][r] * ivv[r];
    }
  }
}

__global__ __launch_bounds__(256, 4) void k_attn(
    const __half* __restrict__ dq, const __half* __restrict__ dk,
    const float2* __restrict__ nq, const float2* __restrict__ nk,
    const __half* __restrict__ v, const __half* __restrict__ KVt,
    const float* __restrict__ Kpre, float* __restrict__ outb) {
  __shared__ __align__(16) char smem[40320];
  if (blockIdx.y == 0)
    attn_body<0>(dq, dk, nq, nk, v, KVt, Kpre, outb, smem);
  else
    attn_body<1>(dq, dk, nq, nk, v, KVt, Kpre, outb, smem);
}

// ---------------------------------------------------------------------------
// S5a (MFMA): x = out @ w_o^T + h (NT, 8192x512, K=512) -> d_out (fp32)
// ---------------------------------------------------------------------------
__global__ __launch_bounds__(256) void k_oproj(
    const float* __restrict__ A, const float* __restrict__ Wo,
    const float* __restrict__ hres, float* __restrict__ xout) {
  __shared__ __align__(16) char smem[34816];
  _Float16* Ah = (_Float16*)smem;            // [128][40]
  _Float16* Bh = (_Float16*)(smem + 10240);  // [128][40]
  _Float16* Oh = (_Float16*)smem;            // [128][136] (epilogue alias)

  const int tid = threadIdx.x;
  const int row0 = blockIdx.x * 128;
  const int col0 = blockIdx.y * 128;
  const int lane = tid & 63, wv = tid >> 6;
  const int ln15 = lane & 15, quad = lane >> 4;
  const int m0 = wv * 32;
  const int srow = tid >> 1, sc = (tid & 1) * 16;

  f32x4 Cacc[2][8];
  const f32x4 z4 = {0.f, 0.f, 0.f, 0.f};
#pragma unroll
  for (int mi = 0; mi < 2; ++mi)
#pragma unroll
    for (int nt = 0; nt < 8; ++nt) Cacc[mi][nt] = z4;

  for (int kt = 0; kt < DMID; kt += 32) {
    cvt16(A + (size_t)(row0 + srow) * DMID + kt + sc, &Ah[srow * 40 + sc]);
    cvt16(Wo + (size_t)(col0 + srow) * DMID + kt + sc, &Bh[srow * 40 + sc]);
    __syncthreads();
    f16x8 a0 = *(const f16x8*)&Ah[(m0 + ln15) * 40 + quad * 8];
    f16x8 a1 = *(const f16x8*)&Ah[(m0 + 16 + ln15) * 40 + quad * 8];
#pragma unroll
    for (int nt = 0; nt < 8; ++nt) {
      f16x8 bf = *(const f16x8*)&Bh[(nt * 16 + ln15) * 40 + quad * 8];
      Cacc[0][nt] = __builtin_amdgcn_mfma_f32_16x16x32_f16(a0, bf, Cacc[0][nt], 0, 0, 0);
      Cacc[1][nt] = __builtin_amdgcn_mfma_f32_16x16x32_f16(a1, bf, Cacc[1][nt], 0, 0, 0);
    }
    __syncthreads();
  }
#pragma unroll
  for (int mi = 0; mi < 2; ++mi)
#pragma unroll
    for (int nt = 0; nt < 8; ++nt)
#pragma unroll
      for (int r = 0; r < 4; ++r)
        Oh[(m0 + mi * 16 + quad * 4 + r) * 136 + nt * 16 + ln15] =
            (_Float16)Cacc[mi][nt][r];
  __syncthreads();
  const int tr = tid >> 4, tc = tid & 15;
#pragma unroll
  for (int i = 0; i < 8; ++i) {
    int lrow = tr * 8 + i;
    int grow = row0 + lrow;
    size_t base = (size_t)grow * 512 + col0 + tc * 8;
    f16x8 o = *(const f16x8*)&Oh[lrow * 136 + tc * 8];
    float4 h0 = *(const float4*)(hres + base);
    float4 h1 = *(const float4*)(hres + base + 4);
    *(float4*)(xout + base) =
        make_float4((float)o[0] + h0.x, (float)o[1] + h0.y,
                    (float)o[2] + h0.z, (float)o[3] + h0.w);
    *(float4*)(xout + base + 4) =
        make_float4((float)o[4] + h1.x, (float)o[5] + h1.y,
                    (float)o[6] + h1.z, (float)o[7] + h1.w);
  }
}

// S5b: in-place LayerNorm over last dim (512).
__global__ __launch_bounds__(256) void k_ln(float* __restrict__ x,
                                            const float* __restrict__ g,
                                            const float* __restrict__ bta) {
  __shared__ float ws_[4], wq_[4];
  const int row = blockIdx.x;
  const int tid = threadIdx.x;
  float2 vv = *(const float2*)(x + (size_t)row * 512 + tid * 2);
  float s = vv.x + vv.y;
  float sq = vv.x * vv.x + vv.y * vv.y;
#pragma unroll
  for (int off = 1; off < 64; off <<= 1) {
    s += __shfl_xor(s, off, 64);
    sq += __shfl_xor(sq, off, 64);
  }
  if ((tid & 63) == 0) { ws_[tid >> 6] = s; wq_[tid >> 6] = sq; }
  __syncthreads();
  s = ws_[0] + ws_[1] + ws_[2] + ws_[3];
  sq = wq_[0] + wq_[1] + wq_[2] + wq_[3];
  float mu = s * (1.f / 512.f);
  float var = sq * (1.f / 512.f) - mu * mu;
  float rstd = rsqrtf(var + EPS_LN);
  int c = tid * 2;
  float2 o;
  o.x = (vv.x - mu) * rstd * g[c] + bta[c];
  o.y = (vv.y - mu) * rstd * g[c + 1] + bta[c + 1];
  *(float2*)(x + (size_t)row * 512 + c) = o;
}

// ---------------------------------------------------------------------------
extern "C" void kernel_launch(void* const* d_in, const int* in_sizes, int n_in,
                              void* d_out, int out_size, void* d_ws,
                              size_t ws_size, hipStream_t stream) {
  const float* h    = (const float*)d_in[0];
  const float* wqkv = (const float*)d_in[1];
  const float* wo   = (const float*)d_in[2];
  const float* g    = (const float*)d_in[3];
  const float* bta  = (const float*)d_in[4];
  const float* proj = (const float*)d_in[5];
  float* out = (float*)d_out;
  char* wsb = (char*)d_ws;

  __half* q   = (__half*)(wsb + 0);           //  8,388,608 B
  __half* kb  = (__half*)(wsb + 8388608);     //  8,388,608 B
  __half* vb  = (__half*)(wsb + 16777216);    //  8,388,608 B
  __half* dq  = (__half*)(wsb + 25165824);    // 33,554,432 B
  __half* dk  = (__half*)(wsb + 58720256);    // 33,554,432 B
  float2* nq  = (float2*)(wsb + 92274688);    //    524,288 B
  float2* nk  = (float2*)(wsb + 92798976);    //    524,288 B
  __half* KVt = (__half*)(wsb + 93323264);    // 33,554,432 B  (cidx,d,feat)
  float*  Ks  = (float*)(wsb + 126877696);    //  1,048,576 B
  __half* pT  = (__half*)(wsb + 127926272);   //     32,768 B
  float* outb = (float*)(wsb + 0);            // aliases q+kb (dead by then)

  if (ws_size < 127959040ull) {
    float val = 1000.0f + (float)(ws_size >> 20);
    k_diag<<<(out_size + 255) / 256, 256, 0, stream>>>(out, out_size, val);
    return;
  }

  k_ptr  <<<dim3(64), 256, 0, stream>>>(proj, pT);
  k_qkv  <<<dim3(64, 12), 256, 0, stream>>>(h, wqkv, q, kb, vb);
  k_dgemm<<<dim3(1024, 2), 256, 0, stream>>>(q, kb, pT, dq, dk, nq, nk);
  k_kv   <<<dim3(512, 4), 256, 0, stream>>>(dk, nk, vb, KVt, Ks);
  k_scan <<<dim3(32, 8), 256, 0, stream>>>((__half2*)KVt, Ks);
  k_attn <<<dim3(512, 2), 256, 0, stream>>>(dq, dk, nq, nk, vb, KVt, Ks, outb);
  k_oproj<<<dim3(64, 4), 256, 0, stream>>>(outb, wo, h, out);
  k_ln   <<<dim3(8192), 256, 0, stream>>>(out, g, bta);
}